// Round 8
// baseline (377.961 us; speedup 1.0000x reference)
//
#include <hip/hip_runtime.h>
#include <hip/hip_bf16.h>
#include <stdint.h>

#define DEV __device__ __forceinline__

typedef unsigned short ushort_t;
typedef __attribute__((ext_vector_type(8))) short bf16x8;  // 8 bf16 = 4 VGPRs
typedef __attribute__((ext_vector_type(4))) float f32x4;

// hardware packed f32->bf16 (RNE), 1 VALU inst (gfx950 v_cvt_pk_bf16_f32)
DEV uint32_t f2bf2(float lo, float hi) {
  uint32_t d;
  asm("v_cvt_pk_bf16_f32 %0, %1, %2" : "=v"(d) : "v"(lo), "v"(hi));
  return d;
}
DEV ushort_t f2bf(float f) { return (ushort_t)f2bf2(f, f); }

DEV void gload_lds16(const void* gp, void* lp) {
  __builtin_amdgcn_global_load_lds(
      (__attribute__((address_space(1))) void*)(void*)(uintptr_t)gp,
      (__attribute__((address_space(3))) void*)lp, 16, 0, 0);
}

// ---------------- fused weight f32 -> bf16 conversion (all 6 weights, 1 launch) ----
__global__ __launch_bounds__(256) void cvt_all(
    const float* __restrict__ Wq, const float* __restrict__ Wk,
    const float* __restrict__ Wv, const float* __restrict__ Wo,
    const float* __restrict__ W1, const float* __restrict__ W2,
    ushort_t* __restrict__ WqB, ushort_t* __restrict__ WKVB,
    ushort_t* __restrict__ WoB, ushort_t* __restrict__ W1B,
    ushort_t* __restrict__ W2B) {
  int i = blockIdx.x * 256 + threadIdx.x;  // float4 index over concatenated weights
  const float* src; ushort_t* dst; int j;
  if (i < 262144)            { src = Wq; dst = WqB;           j = i; }
  else if (i < 524288)       { src = Wk; dst = WKVB;          j = i - 262144; }
  else if (i < 786432)       { src = Wv; dst = WKVB + 1048576; j = i - 524288; }
  else if (i < 1048576)      { src = Wo; dst = WoB;           j = i - 786432; }
  else if (i < 2097152)      { src = W1; dst = W1B;           j = i - 1048576; }
  else                       { src = W2; dst = W2B;           j = i - 2097152; }
  float4 v = ((const float4*)src)[j];
  uint2 o; o.x = f2bf2(v.x, v.y); o.y = f2bf2(v.z, v.w);
  ((uint2*)dst)[j] = o;
}

// ---------------- LayerNorm (D=1024) -> bf16 ----------------
DEV void ln_row(const float* __restrict__ x, const float* __restrict__ g,
                const float* __restrict__ be, ushort_t* __restrict__ out, int row) {
  const int t = threadIdx.x;
  const float4 v = ((const float4*)(x + (size_t)row * 1024))[t];
  float s = v.x + v.y + v.z + v.w;
  float sq = v.x * v.x + v.y * v.y + v.z * v.z + v.w * v.w;
#pragma unroll
  for (int d = 1; d < 64; d <<= 1) { s += __shfl_xor(s, d); sq += __shfl_xor(sq, d); }
  __shared__ float sm[8];
  const int w = t >> 6, lane = t & 63;
  if (lane == 0) { sm[w * 2] = s; sm[w * 2 + 1] = sq; }
  __syncthreads();
  s = sm[0] + sm[2] + sm[4] + sm[6];
  sq = sm[1] + sm[3] + sm[5] + sm[7];
  const float mean = s * (1.f / 1024.f);
  const float var = sq * (1.f / 1024.f) - mean * mean;
  const float rstd = rsqrtf(var + 1e-5f);
  const float4 gv = ((const float4*)g)[t];
  const float4 bv = ((const float4*)be)[t];
  uint2 o;
  o.x = f2bf2((v.x - mean) * rstd * gv.x + bv.x, (v.y - mean) * rstd * gv.y + bv.y);
  o.y = f2bf2((v.z - mean) * rstd * gv.z + bv.z, (v.w - mean) * rstd * gv.w + bv.w);
  ((uint2*)(out + (size_t)row * 1024))[t] = o;
}

__global__ __launch_bounds__(256) void ln_bf16(const float* __restrict__ x,
                                               const float* __restrict__ g,
                                               const float* __restrict__ be,
                                               ushort_t* __restrict__ out) {
  ln_row(x, g, be, out, blockIdx.x);
}

__global__ __launch_bounds__(256) void ln_fused(
    const float* __restrict__ x_q, const float* __restrict__ x_kv,
    const float* __restrict__ qg, const float* __restrict__ qb,
    const float* __restrict__ kg, const float* __restrict__ kb,
    ushort_t* __restrict__ oq, ushort_t* __restrict__ okv) {
  const int r = blockIdx.x;
  if (r < 4096) ln_row(x_q, qg, qb, oq, r);
  else ln_row(x_kv, kg, kb, okv, r - 4096);
}

// XCD swizzle: cyclic wg->XCD dispatch means lin%8 = XCD. Remap so each XCD's
// resident blocks share gy/8 consecutive M-row tiles (A-tile / KV L2 locality).
DEV void xcd_remap(int gx, int gy, int& bx, int& by) {
  const int lin = by * gx + bx;
  const int xcd = lin & 7, s = lin >> 3;
  by = xcd * (gy >> 3) + s / gx;
  bx = s % gx;
}

// ---------------- GEMM: out[m,n] = sum_k A[m,k]*W[n,k] (+bias, epilogues) ----------------
// BK=64, XOR-8 chunk swizzle (conflict-free b128 fragment reads), DOUBLE-BUFFERED
// staging: tile k+1's global_load_lds issued before tile k's compute, so the
// end-of-iter barrier drains loads that had a full compute phase in flight.
enum { EPI_BF16 = 0, EPI_KV = 1, EPI_RESID = 2, EPI_GELU = 3 };

template <int TN, int EPI>
__global__ __launch_bounds__(256, 2) void gemm_bt(
    const ushort_t* __restrict__ A,    // [M][K] bf16
    const ushort_t* __restrict__ Wb,   // [N][K] bf16
    const float* __restrict__ bias,    // [N] (or K-half bias for EPI_KV)
    const float* __restrict__ bias2,   // EPI_KV: V bias
    const float* __restrict__ resid,   // [M][N] f32 or null
    void* __restrict__ outp, void* __restrict__ outp2,
    int M, int N, int K, float oscale) {
  constexpr int NI = (TN == 128) ? 4 : 2;
  constexpr int NB = TN / 32;
  __shared__ ushort_t As[2][128 * 64];  // 32 KB
  __shared__ ushort_t Bs[2][TN * 64];   // 32/16 KB
  const int t = threadIdx.x;
  const int w = t >> 6, lane = t & 63;
  const int qd = lane >> 4, ql = lane & 15;
  int bx = blockIdx.x, by = blockIdx.y;
  xcd_remap(gridDim.x, gridDim.y, bx, by);
  const int m0 = by * 128, n0 = bx * TN;
  const int wm = (TN == 128) ? (w >> 1) * 64 : w * 32;
  const int wn = (TN == 128) ? (w & 1) * 64 : 0;
  const int sw = ql & 7;

  // hoisted staging pointers (advance by BK=64 elems per iter)
  const ushort_t* pa[4];
#pragma unroll
  for (int p = 0; p < 4; p++) {
    int n = p * 256 + t, row = n >> 3, c = (n & 7) ^ (row & 7);
    pa[p] = A + (size_t)(m0 + row) * K + c * 8;
  }
  const ushort_t* pb[NB];
#pragma unroll
  for (int p = 0; p < NB; p++) {
    int n = p * 256 + t, row = n >> 3, c = (n & 7) ^ (row & 7);
    pb[p] = Wb + (size_t)(n0 + row) * K + c * 8;
  }

  // preload tile 0
#pragma unroll
  for (int p = 0; p < 4; p++) { gload_lds16(pa[p], &As[0][(p * 256 + t) * 8]); pa[p] += 64; }
#pragma unroll
  for (int p = 0; p < NB; p++) { gload_lds16(pb[p], &Bs[0][(p * 256 + t) * 8]); pb[p] += 64; }
  __syncthreads();

  f32x4 acc[NI][4] = {};
  const int NIT = K >> 6;
  int cur = 0;

  for (int it = 0; it < NIT; ++it) {
    if (it + 1 < NIT) {  // prefetch next tile into the other buffer
#pragma unroll
      for (int p = 0; p < 4; p++) { gload_lds16(pa[p], &As[1 ^ cur][(p * 256 + t) * 8]); pa[p] += 64; }
#pragma unroll
      for (int p = 0; p < NB; p++) { gload_lds16(pb[p], &Bs[1 ^ cur][(p * 256 + t) * 8]); pb[p] += 64; }
    }
    const ushort_t* Ac = As[cur];
    const ushort_t* Bc = Bs[cur];
#pragma unroll
    for (int ks = 0; ks < 2; ks++) {
      bf16x8 af[NI], bf[4];
#pragma unroll
      for (int i = 0; i < NI; i++)
        af[i] = *(const bf16x8*)&Ac[(wm + i * 16 + ql) * 64 + ((ks * 4 + qd) ^ sw) * 8];
#pragma unroll
      for (int j = 0; j < 4; j++)
        bf[j] = *(const bf16x8*)&Bc[(wn + j * 16 + ql) * 64 + ((ks * 4 + qd) ^ sw) * 8];
#pragma unroll
      for (int i = 0; i < NI; i++)
#pragma unroll
        for (int j = 0; j < 4; j++)
          acc[i][j] = __builtin_amdgcn_mfma_f32_16x16x32_bf16(af[i], bf[j], acc[i][j], 0, 0, 0);
    }
    __syncthreads();  // readers of cur done + prefetch drained
    cur ^= 1;
  }

#pragma unroll
  for (int i = 0; i < NI; i++) {
    const int mr = m0 + wm + i * 16 + qd * 4;
#pragma unroll
    for (int j = 0; j < 4; j++) {
      const int col = n0 + wn + j * 16 + ql;
      f32x4 v = acc[i][j];
      if constexpr (EPI == EPI_BF16) {
        const float bb = bias[col];
        ushort_t* o = (ushort_t*)outp;
#pragma unroll
        for (int r = 0; r < 4; r++) o[(size_t)(mr + r) * N + col] = f2bf((v[r] + bb) * oscale);
      } else if constexpr (EPI == EPI_KV) {
        if (col < 1024) {  // K half -> [4096][1024] bf16
          const float bb = bias[col];
          ushort_t* o = (ushort_t*)outp;
#pragma unroll
          for (int r = 0; r < 4; r++) o[(size_t)(mr + r) * 1024 + col] = f2bf(v[r] + bb);
        } else {  // V half -> V^T [B=2][H=16][HD=64][L=2048] bf16
          const int vc = col - 1024;
          const float bb = bias2[vc];
          const int h = vc >> 6, d = vc & 63;
          const int b = mr >> 11, l0 = mr & 2047;
          uint2 pk;
          pk.x = f2bf2(v[0] + bb, v[1] + bb);
          pk.y = f2bf2(v[2] + bb, v[3] + bb);
          *(uint2*)((ushort_t*)outp2 + ((((size_t)b * 16 + h) * 64 + d) * 2048 + l0)) = pk;
        }
      } else if constexpr (EPI == EPI_RESID) {
        const float bb = bias[col];
        float* o = (float*)outp;
#pragma unroll
        for (int r = 0; r < 4; r++) {
          size_t idx = (size_t)(mr + r) * N + col;
          o[idx] = resid[idx] + v[r] + bb;
        }
      } else {  // EPI_GELU (exact, erf)
        const float bb = bias[col];
        ushort_t* o = (ushort_t*)outp;
#pragma unroll
        for (int r = 0; r < 4; r++) {
          float x = v[r] + bb;
          float gx = 0.5f * x * (1.0f + erff(x * 0.70710678118654752f));
          o[(size_t)(mr + r) * N + col] = f2bf(gx);
        }
      }
    }
  }
}

// ---------------- flash attention with softmax-1, fixed m=0, S^T orientation ------
// Q pre-scaled by 0.125*log2(e) in the Q-projection; p = exp2(s_hat) = exp(q.k/8).
// S^T = K.Q^T (swapped MFMA operands) so P packs into b64 LDS writes. XCD swizzle
// groups 4 heads per XCD -> K/V working set 2 MB fits the 4 MB per-XCD L2.
__global__ __launch_bounds__(256, 2) void flash_attn(const ushort_t* __restrict__ Qg,
                                                     const ushort_t* __restrict__ Kg,
                                                     const ushort_t* __restrict__ VTg,
                                                     ushort_t* __restrict__ Og) {
  __shared__ ushort_t QPs[128 * 64];    // 16 KB: Q tile, then P[n][l] (Q dead after hoist)
  __shared__ ushort_t Ks[2][64 * 64];   // 16 KB (dbuf K tile [l][d])
  __shared__ ushort_t Vs[2][64 * 64];   // 16 KB (dbuf V^T tile [d][l])
  const int t = threadIdx.x, w = t >> 6, lane = t & 63;
  const int qd = lane >> 4, ql = lane & 15;
  int bx = blockIdx.x, bh = blockIdx.y;
  xcd_remap(gridDim.x, gridDim.y, bx, bh);
  const int b = bh >> 4, h = bh & 15;
  const int n0 = bx * 128;
  const ushort_t* Qp = Qg + ((size_t)b * 2048 + n0) * 1024 + h * 64;
  const ushort_t* Kp = Kg + (size_t)b * 2048 * 1024 + h * 64;
  const ushort_t* Vp = VTg + (size_t)bh * 64 * 2048;
  const int sw = ql & 7;  // read-side swizzle key

  // hoisted staging pointers: K advances 64 rows, V 64 cols per tile
  const ushort_t* kp2[2];
  const ushort_t* vp2[2];
#pragma unroll
  for (int p = 0; p < 2; p++) {
    int n = p * 256 + t, row = n >> 3, c = (n & 7) ^ (row & 7);
    kp2[p] = Kp + (size_t)row * 1024 + c * 8;
    vp2[p] = Vp + (size_t)row * 2048 + c * 8;
  }

  // stage Q (swizzled) + K/V tile 0
#pragma unroll
  for (int p = 0; p < 4; p++) {
    int n = p * 256 + t, row = n >> 3, c = (n & 7) ^ (row & 7);
    gload_lds16(Qp + (size_t)row * 1024 + c * 8, &QPs[n * 8]);
  }
#pragma unroll
  for (int p = 0; p < 2; p++) {
    int n = p * 256 + t;
    gload_lds16(kp2[p], &Ks[0][n * 8]);
    gload_lds16(vp2[p], &Vs[0][n * 8]);
    kp2[p] += 64 * 1024;
    vp2[p] += 64;
  }
  __syncthreads();

  // hoist Q fragments (loop-invariant); Qs LDS dead afterwards
  bf16x8 aq[2][2];
#pragma unroll
  for (int i = 0; i < 2; i++)
#pragma unroll
    for (int ks = 0; ks < 2; ks++)
      aq[i][ks] = *(const bf16x8*)&QPs[(w * 32 + i * 16 + ql) * 64 + ((ks * 4 + qd) ^ sw) * 8];
  __syncthreads();  // all aq reads done before any wave writes P into QPs

  f32x4 accO[2][4] = {};
  float lro2[2] = {0.f, 0.f};  // denom partials for n = w*32 + i*16 + ql (quad-partial)

  int cur = 0;
  for (int lt = 0; lt < 32; ++lt) {
    if (lt + 1 < 32) {
#pragma unroll
      for (int p = 0; p < 2; p++) {
        int n = p * 256 + t;
        gload_lds16(kp2[p], &Ks[1 ^ cur][n * 8]);
        gload_lds16(vp2[p], &Vs[1 ^ cur][n * 8]);
        kp2[p] += 64 * 1024;
        vp2[p] += 64;
      }
    }
    const ushort_t* Kc = Ks[cur];
    const ushort_t* Vc = Vs[cur];

    // S^T = K (Q*0.1803)^T : accS[j][i], rows l = j*16+qd*4+r, cols n = i*16+ql
    f32x4 accS[4][2] = {};
#pragma unroll
    for (int ks = 0; ks < 2; ks++) {
      bf16x8 bk[4];
#pragma unroll
      for (int j = 0; j < 4; j++)
        bk[j] = *(const bf16x8*)&Kc[(j * 16 + ql) * 64 + ((ks * 4 + qd) ^ sw) * 8];
#pragma unroll
      for (int j = 0; j < 4; j++)
#pragma unroll
        for (int i = 0; i < 2; i++)
          accS[j][i] = __builtin_amdgcn_mfma_f32_16x16x32_bf16(bk[j], aq[i][ks], accS[j][i], 0, 0, 0);
    }

    // p = exp2(s_hat); denom += p; pack 4 consecutive l -> one b64 P-write
#pragma unroll
    for (int j = 0; j < 4; j++)
#pragma unroll
      for (int i = 0; i < 2; i++) {
        f32x4 p;
#pragma unroll
        for (int r = 0; r < 4; r++) {
          p[r] = __builtin_amdgcn_exp2f(accS[j][i][r]);
          lro2[i] += p[r];
        }
        const int n = w * 32 + i * 16 + ql;
        // l = j*16 + qd*4 + r; 16B chunk c = j*2 + (qd>>1), swizzled c^(n&7)=c^sw
        const int coff = (((j * 2 + (qd >> 1)) ^ sw) << 3) + ((qd & 1) << 2);
        uint2 pk; pk.x = f2bf2(p[0], p[1]); pk.y = f2bf2(p[2], p[3]);
        *(uint2*)&QPs[n * 64 + coff] = pk;
      }

    // O += P V (P rows intra-wave; V^T B-frags from Vs)
#pragma unroll
    for (int ks = 0; ks < 2; ks++) {
      bf16x8 ap[2], bv[4];
#pragma unroll
      for (int i = 0; i < 2; i++)
        ap[i] = *(const bf16x8*)&QPs[(w * 32 + i * 16 + ql) * 64 + ((ks * 4 + qd) ^ sw) * 8];
#pragma unroll
      for (int jo = 0; jo < 4; jo++)
        bv[jo] = *(const bf16x8*)&Vc[(jo * 16 + ql) * 64 + ((ks * 4 + qd) ^ sw) * 8];
#pragma unroll
      for (int i = 0; i < 2; i++)
#pragma unroll
        for (int jo = 0; jo < 4; jo++)
          accO[i][jo] = __builtin_amdgcn_mfma_f32_16x16x32_bf16(ap[i], bv[jo], accO[i][jo], 0, 0, 0);
    }

    __syncthreads();  // K/V[cur] readers done + next-tile loads drained
    cur ^= 1;
  }

  // finish denominators: sum across quads (each quad held disjoint l ranges)
  float dn[2];
#pragma unroll
  for (int i = 0; i < 2; i++) {
    float l = lro2[i];
    l += __shfl_xor(l, 16);
    l += __shfl_xor(l, 32);
    dn[i] = l + 1.0f;  // +1: implicit zero logit of softmax-1
  }

#pragma unroll
  for (int i = 0; i < 2; i++)
#pragma unroll
    for (int r = 0; r < 4; r++) {
      // denom for row n' = qd*4+r lives in lane ql = n' (quad-uniform after reduce)
      const float inv = 1.0f / __shfl(dn[i], qd * 4 + r);
      const int row = n0 + w * 32 + i * 16 + qd * 4 + r;
#pragma unroll
      for (int jo = 0; jo < 4; jo++)
        Og[((size_t)b * 2048 + row) * 1024 + h * 64 + jo * 16 + ql] =
            f2bf(accO[i][jo][r] * inv);
    }
}

// ---------------- launch ----------------
extern "C" void kernel_launch(void* const* d_in, const int* in_sizes, int n_in,
                              void* d_out, int out_size, void* d_ws, size_t ws_size,
                              hipStream_t stream) {
  const float* x_q = (const float*)d_in[0];
  const float* x_kv = (const float*)d_in[1];
  const float* qn_g = (const float*)d_in[2];
  const float* qn_b = (const float*)d_in[3];
  const float* kvn_g = (const float*)d_in[4];
  const float* kvn_b = (const float*)d_in[5];
  const float* Wq = (const float*)d_in[6];
  const float* bq = (const float*)d_in[7];
  const float* Wk = (const float*)d_in[8];
  const float* bk = (const float*)d_in[9];
  const float* Wv = (const float*)d_in[10];
  const float* bv = (const float*)d_in[11];
  const float* Wo = (const float*)d_in[12];
  const float* bo = (const float*)d_in[13];
  const float* n2_g = (const float*)d_in[14];
  const float* n2_b = (const float*)d_in[15];
  const float* W1 = (const float*)d_in[16];
  const float* b1 = (const float*)d_in[17];
  const float* W2 = (const float*)d_in[18];
  const float* b2 = (const float*)d_in[19];

  char* ws = (char*)d_ws;
  const size_t MB = 1ull << 20;
  ushort_t* WqB = (ushort_t*)(ws + 0 * MB);    // 2 MB
  ushort_t* WKVB = (ushort_t*)(ws + 2 * MB);   // 4 MB ([Wk;Wv] stacked, 2048x1024)
  ushort_t* WoB = (ushort_t*)(ws + 6 * MB);    // 2 MB
  ushort_t* W1B = (ushort_t*)(ws + 8 * MB);    // 8 MB
  ushort_t* W2B = (ushort_t*)(ws + 16 * MB);   // 8 MB
  ushort_t* LNQ = (ushort_t*)(ws + 24 * MB);
  ushort_t* LNKV = (ushort_t*)(ws + 32 * MB);
  ushort_t* Qb = (ushort_t*)(ws + 40 * MB);
  ushort_t* Kb = (ushort_t*)(ws + 48 * MB);
  ushort_t* VTb = (ushort_t*)(ws + 56 * MB);
  ushort_t* AOb = (ushort_t*)(ws + 64 * MB);
  float* Xf = (float*)(ws + 72 * MB);          // 16 MB
  ushort_t* LN2 = (ushort_t*)(ws + 88 * MB);
  ushort_t* Hb = (ushort_t*)(ws + 24 * MB);    // 32 MB, overlays LNQ/LNKV/Qb/Kb (dead by MLP1)

  // fold softmax scale (1/8) and exp->exp2 (log2 e) into the Q projection
  const float QSCALE = 0.18033688011112042f;  // 0.125 * log2(e)

  cvt_all<<<12288, 256, 0, stream>>>(Wq, Wk, Wv, Wo, W1, W2, WqB, WKVB, WoB, W1B, W2B);
  ln_fused<<<8192, 256, 0, stream>>>(x_q, x_kv, qn_g, qn_b, kvn_g, kvn_b, LNQ, LNKV);

  gemm_bt<64, EPI_BF16><<<dim3(16, 32), 256, 0, stream>>>(
      LNQ, WqB, bq, nullptr, nullptr, Qb, nullptr, 4096, 1024, 1024, QSCALE);
  gemm_bt<128, EPI_KV><<<dim3(16, 32), 256, 0, stream>>>(
      LNKV, WKVB, bk, bv, nullptr, Kb, VTb, 4096, 2048, 1024, 1.0f);

  flash_attn<<<dim3(16, 32), 256, 0, stream>>>(Qb, Kb, VTb, AOb);

  gemm_bt<64, EPI_RESID><<<dim3(16, 32), 256, 0, stream>>>(
      AOb, WoB, bo, nullptr, x_q, Xf, nullptr, 4096, 1024, 1024, 1.0f);
  ln_bf16<<<4096, 256, 0, stream>>>(Xf, n2_g, n2_b, LN2);
  gemm_bt<128, EPI_GELU><<<dim3(32, 32), 256, 0, stream>>>(
      LN2, W1B, b1, nullptr, nullptr, Hb, nullptr, 4096, 4096, 1024, 1.0f);
  gemm_bt<64, EPI_RESID><<<dim3(16, 32), 256, 0, stream>>>(
      Hb, W2B, b2, nullptr, Xf, (float*)d_out, nullptr, 4096, 1024, 4096, 1.0f);
}

// Round 9
// 366.573 us; speedup vs baseline: 1.0311x; 1.0311x over previous
//
#include <hip/hip_runtime.h>
#include <hip/hip_bf16.h>
#include <stdint.h>

#define DEV __device__ __forceinline__

typedef unsigned short ushort_t;
typedef __attribute__((ext_vector_type(8))) short bf16x8;  // 8 bf16 = 4 VGPRs
typedef __attribute__((ext_vector_type(4))) float f32x4;

// hardware packed f32->bf16 (RNE), 1 VALU inst (gfx950 v_cvt_pk_bf16_f32)
DEV uint32_t f2bf2(float lo, float hi) {
  uint32_t d;
  asm("v_cvt_pk_bf16_f32 %0, %1, %2" : "=v"(d) : "v"(lo), "v"(hi));
  return d;
}
DEV ushort_t f2bf(float f) { return (ushort_t)f2bf2(f, f); }

DEV void gload_lds16(const void* gp, void* lp) {
  __builtin_amdgcn_global_load_lds(
      (__attribute__((address_space(1))) void*)(void*)(uintptr_t)gp,
      (__attribute__((address_space(3))) void*)lp, 16, 0, 0);
}

// ---------------- fused weight f32 -> bf16 conversion (all 6 weights, 1 launch) ----
// Wq/Wk/Wv stacked into one 3072x1024 buffer for the merged QKV GEMM.
__global__ __launch_bounds__(256) void cvt_all(
    const float* __restrict__ Wq, const float* __restrict__ Wk,
    const float* __restrict__ Wv, const float* __restrict__ Wo,
    const float* __restrict__ W1, const float* __restrict__ W2,
    ushort_t* __restrict__ WQKVB, ushort_t* __restrict__ WoB,
    ushort_t* __restrict__ W1B, ushort_t* __restrict__ W2B) {
  int i = blockIdx.x * 256 + threadIdx.x;  // float4 index over concatenated weights
  const float* src; ushort_t* dst; int j;
  if (i < 262144)            { src = Wq; dst = WQKVB;            j = i; }
  else if (i < 524288)       { src = Wk; dst = WQKVB + 1048576;  j = i - 262144; }
  else if (i < 786432)       { src = Wv; dst = WQKVB + 2097152;  j = i - 524288; }
  else if (i < 1048576)      { src = Wo; dst = WoB;              j = i - 786432; }
  else if (i < 2097152)      { src = W1; dst = W1B;              j = i - 1048576; }
  else                       { src = W2; dst = W2B;              j = i - 2097152; }
  float4 v = ((const float4*)src)[j];
  uint2 o; o.x = f2bf2(v.x, v.y); o.y = f2bf2(v.z, v.w);
  ((uint2*)dst)[j] = o;
}

// ---------------- LayerNorm (D=1024) -> bf16 ----------------
DEV void ln_row(const float* __restrict__ x, const float* __restrict__ g,
                const float* __restrict__ be, ushort_t* __restrict__ out, int row) {
  const int t = threadIdx.x;
  const float4 v = ((const float4*)(x + (size_t)row * 1024))[t];
  float s = v.x + v.y + v.z + v.w;
  float sq = v.x * v.x + v.y * v.y + v.z * v.z + v.w * v.w;
#pragma unroll
  for (int d = 1; d < 64; d <<= 1) { s += __shfl_xor(s, d); sq += __shfl_xor(sq, d); }
  __shared__ float sm[8];
  const int w = t >> 6, lane = t & 63;
  if (lane == 0) { sm[w * 2] = s; sm[w * 2 + 1] = sq; }
  __syncthreads();
  s = sm[0] + sm[2] + sm[4] + sm[6];
  sq = sm[1] + sm[3] + sm[5] + sm[7];
  const float mean = s * (1.f / 1024.f);
  const float var = sq * (1.f / 1024.f) - mean * mean;
  const float rstd = rsqrtf(var + 1e-5f);
  const float4 gv = ((const float4*)g)[t];
  const float4 bv = ((const float4*)be)[t];
  uint2 o;
  o.x = f2bf2((v.x - mean) * rstd * gv.x + bv.x, (v.y - mean) * rstd * gv.y + bv.y);
  o.y = f2bf2((v.z - mean) * rstd * gv.z + bv.z, (v.w - mean) * rstd * gv.w + bv.w);
  ((uint2*)(out + (size_t)row * 1024))[t] = o;
}

__global__ __launch_bounds__(256) void ln_bf16(const float* __restrict__ x,
                                               const float* __restrict__ g,
                                               const float* __restrict__ be,
                                               ushort_t* __restrict__ out) {
  ln_row(x, g, be, out, blockIdx.x);
}

__global__ __launch_bounds__(256) void ln_fused(
    const float* __restrict__ x_q, const float* __restrict__ x_kv,
    const float* __restrict__ qg, const float* __restrict__ qb,
    const float* __restrict__ kg, const float* __restrict__ kb,
    ushort_t* __restrict__ oq, ushort_t* __restrict__ okv) {
  const int r = blockIdx.x;
  if (r < 4096) ln_row(x_q, qg, qb, oq, r);
  else ln_row(x_kv, kg, kb, okv, r - 4096);
}

// XCD swizzle: cyclic wg->XCD dispatch means lin%8 = XCD. Remap so each XCD's
// resident blocks share gy/8 consecutive M-row tiles (A-tile / KV L2 locality).
DEV void xcd_remap(int gx, int gy, int& bx, int& by) {
  const int lin = by * gx + bx;
  const int xcd = lin & 7, s = lin >> 3;
  by = xcd * (gy >> 3) + s / gx;
  bx = s % gx;
}

// ---------------- GEMM: out[m,n] = sum_k A[m,k]*W[n,k] (+bias, epilogues) ----------------
// Double-buffered staging (prefetch tile k+1 before computing tile k). TN=128 uses
// BK=32 (32 KB LDS -> 3 blocks/CU, the m97-proven config); TN=64 uses BK=64 (48 KB).
// Source-chunk XOR swizzle keeps global_load_lds's linear lane->LDS dst while making
// all ds_read_b128 fragment reads 2-way-or-free on banks:
//   BK=64: chunk c ^ (row&7);  BK=32: chunk c ^ ((row>>1)&3).
enum { EPI_BF16 = 0, EPI_KV = 1, EPI_RESID = 2, EPI_GELU = 3, EPI_QKV = 4 };

template <int TN, int BK, int EPI>
__global__ __launch_bounds__(256, 3) void gemm_bt(
    const ushort_t* __restrict__ A,    // [M][K] bf16
    const ushort_t* __restrict__ A2,   // EPI_QKV: A for n0>=1024 (LNKV)
    const ushort_t* __restrict__ Wb,   // [N][K] bf16
    const float* __restrict__ bias, const float* __restrict__ bias2,
    const float* __restrict__ bias3,
    const float* __restrict__ resid,   // [M][N] f32 or null
    void* __restrict__ outp, void* __restrict__ outp2, void* __restrict__ outp3,
    int M, int N, int K, float oscale) {
  constexpr int NI = (TN == 128) ? 4 : 2;
  constexpr int CH = BK / 8;             // 16B chunks per row
  constexpr int NA = (128 * CH) / 256;   // A staging loads per thread
  constexpr int NBL = (TN * CH) / 256;   // B staging loads per thread
  constexpr int KS = BK / 32;            // mfma K-steps per tile
  __shared__ ushort_t As[2][128 * BK];
  __shared__ ushort_t Bs[2][TN * BK];
  const int t = threadIdx.x;
  const int w = t >> 6, lane = t & 63;
  const int qd = lane >> 4, ql = lane & 15;
  int bx = blockIdx.x, by = blockIdx.y;
  xcd_remap(gridDim.x, gridDim.y, bx, by);
  const int m0 = by * 128, n0 = bx * TN;
  const int wm = (TN == 128) ? (w >> 1) * 64 : w * 32;
  const int wn = (TN == 128) ? (w & 1) * 64 : 0;
  const int sw = (BK == 64) ? (ql & 7) : ((ql >> 1) & 3);  // read-side swizzle key

  const ushort_t* Ause = (EPI == EPI_QKV && n0 >= 1024) ? A2 : A;

  // hoisted staging pointers (advance by BK elems per iter); source chunk swizzled
  const ushort_t* pa[NA];
#pragma unroll
  for (int p = 0; p < NA; p++) {
    int n = p * 256 + t, row = n / CH, c = n % CH;
    int g = (BK == 64) ? (c ^ (row & 7)) : (c ^ ((row >> 1) & 3));
    pa[p] = Ause + (size_t)(m0 + row) * K + g * 8;
  }
  const ushort_t* pb[NBL];
#pragma unroll
  for (int p = 0; p < NBL; p++) {
    int n = p * 256 + t, row = n / CH, c = n % CH;
    int g = (BK == 64) ? (c ^ (row & 7)) : (c ^ ((row >> 1) & 3));
    pb[p] = Wb + (size_t)(n0 + row) * K + g * 8;
  }

  // preload tile 0
#pragma unroll
  for (int p = 0; p < NA; p++) { gload_lds16(pa[p], &As[0][(p * 256 + t) * 8]); pa[p] += BK; }
#pragma unroll
  for (int p = 0; p < NBL; p++) { gload_lds16(pb[p], &Bs[0][(p * 256 + t) * 8]); pb[p] += BK; }
  __syncthreads();

  f32x4 acc[NI][4] = {};
  const int NIT = K / BK;
  int cur = 0;

  for (int it = 0; it < NIT; ++it) {
    if (it + 1 < NIT) {  // prefetch next tile into the other buffer
#pragma unroll
      for (int p = 0; p < NA; p++) { gload_lds16(pa[p], &As[1 ^ cur][(p * 256 + t) * 8]); pa[p] += BK; }
#pragma unroll
      for (int p = 0; p < NBL; p++) { gload_lds16(pb[p], &Bs[1 ^ cur][(p * 256 + t) * 8]); pb[p] += BK; }
    }
    const ushort_t* Ac = As[cur];
    const ushort_t* Bc = Bs[cur];
#pragma unroll
    for (int ks = 0; ks < KS; ks++) {
      bf16x8 af[NI], bf[4];
#pragma unroll
      for (int i = 0; i < NI; i++)
        af[i] = *(const bf16x8*)&Ac[(wm + i * 16 + ql) * BK + ((ks * 4 + qd) ^ sw) * 8];
#pragma unroll
      for (int j = 0; j < 4; j++)
        bf[j] = *(const bf16x8*)&Bc[(wn + j * 16 + ql) * BK + ((ks * 4 + qd) ^ sw) * 8];
#pragma unroll
      for (int i = 0; i < NI; i++)
#pragma unroll
        for (int j = 0; j < 4; j++)
          acc[i][j] = __builtin_amdgcn_mfma_f32_16x16x32_bf16(af[i], bf[j], acc[i][j], 0, 0, 0);
    }
    __syncthreads();  // readers of cur done + prefetch drained
    cur ^= 1;
  }

#pragma unroll
  for (int i = 0; i < NI; i++) {
    const int mr = m0 + wm + i * 16 + qd * 4;
#pragma unroll
    for (int j = 0; j < 4; j++) {
      const int col = n0 + wn + j * 16 + ql;
      f32x4 v = acc[i][j];
      if constexpr (EPI == EPI_BF16) {
        const float bb = bias[col];
        ushort_t* o = (ushort_t*)outp;
#pragma unroll
        for (int r = 0; r < 4; r++) o[(size_t)(mr + r) * N + col] = f2bf((v[r] + bb) * oscale);
      } else if constexpr (EPI == EPI_QKV) {
        if (col < 1024) {  // Q half (pre-scaled by oscale for exp2 softmax)
          const float bb = bias[col];
          ushort_t* o = (ushort_t*)outp;
#pragma unroll
          for (int r = 0; r < 4; r++) o[(size_t)(mr + r) * 1024 + col] = f2bf((v[r] + bb) * oscale);
        } else if (col < 2048) {  // K -> [4096][1024] bf16
          const int c2 = col - 1024;
          const float bb = bias2[c2];
          ushort_t* o = (ushort_t*)outp2;
#pragma unroll
          for (int r = 0; r < 4; r++) o[(size_t)(mr + r) * 1024 + c2] = f2bf(v[r] + bb);
        } else {  // V -> V^T [B=2][H=16][HD=64][L=2048] bf16
          const int vc = col - 2048;
          const float bb = bias3[vc];
          const int h = vc >> 6, d = vc & 63;
          const int b = mr >> 11, l0 = mr & 2047;
          uint2 pk;
          pk.x = f2bf2(v[0] + bb, v[1] + bb);
          pk.y = f2bf2(v[2] + bb, v[3] + bb);
          *(uint2*)((ushort_t*)outp3 + ((((size_t)b * 16 + h) * 64 + d) * 2048 + l0)) = pk;
        }
      } else if constexpr (EPI == EPI_RESID) {
        const float bb = bias[col];
        float* o = (float*)outp;
#pragma unroll
        for (int r = 0; r < 4; r++) {
          size_t idx = (size_t)(mr + r) * N + col;
          o[idx] = resid[idx] + v[r] + bb;
        }
      } else if constexpr (EPI == EPI_GELU) {  // exact, erf
        const float bb = bias[col];
        ushort_t* o = (ushort_t*)outp;
#pragma unroll
        for (int r = 0; r < 4; r++) {
          float x = v[r] + bb;
          float gx = 0.5f * x * (1.0f + erff(x * 0.70710678118654752f));
          o[(size_t)(mr + r) * N + col] = f2bf(gx);
        }
      }
    }
  }
}

// ---------------- flash attention with softmax-1, fixed m=0, S^T orientation ------
// Q pre-scaled by 0.125*log2(e) in the QKV projection; p = exp2(s_hat) = exp(q.k/8).
// S^T = K.Q^T (swapped MFMA operands) so P packs into b64 LDS writes. XCD swizzle
// groups 4 heads per XCD -> K/V working set 2 MB fits the 4 MB per-XCD L2.
__global__ __launch_bounds__(256, 2) void flash_attn(const ushort_t* __restrict__ Qg,
                                                     const ushort_t* __restrict__ Kg,
                                                     const ushort_t* __restrict__ VTg,
                                                     ushort_t* __restrict__ Og) {
  __shared__ ushort_t QPs[128 * 64];    // 16 KB: Q tile, then P[n][l] (Q dead after hoist)
  __shared__ ushort_t Ks[2][64 * 64];   // 16 KB (dbuf K tile [l][d])
  __shared__ ushort_t Vs[2][64 * 64];   // 16 KB (dbuf V^T tile [d][l])
  const int t = threadIdx.x, w = t >> 6, lane = t & 63;
  const int qd = lane >> 4, ql = lane & 15;
  int bx = blockIdx.x, bh = blockIdx.y;
  xcd_remap(gridDim.x, gridDim.y, bx, bh);
  const int b = bh >> 4, h = bh & 15;
  const int n0 = bx * 128;
  const ushort_t* Qp = Qg + ((size_t)b * 2048 + n0) * 1024 + h * 64;
  const ushort_t* Kp = Kg + (size_t)b * 2048 * 1024 + h * 64;
  const ushort_t* Vp = VTg + (size_t)bh * 64 * 2048;
  const int sw = ql & 7;  // read-side swizzle key

  // hoisted staging pointers: K advances 64 rows, V 64 cols per tile
  const ushort_t* kp2[2];
  const ushort_t* vp2[2];
#pragma unroll
  for (int p = 0; p < 2; p++) {
    int n = p * 256 + t, row = n >> 3, c = (n & 7) ^ (row & 7);
    kp2[p] = Kp + (size_t)row * 1024 + c * 8;
    vp2[p] = Vp + (size_t)row * 2048 + c * 8;
  }

  // stage Q (swizzled) + K/V tile 0
#pragma unroll
  for (int p = 0; p < 4; p++) {
    int n = p * 256 + t, row = n >> 3, c = (n & 7) ^ (row & 7);
    gload_lds16(Qp + (size_t)row * 1024 + c * 8, &QPs[n * 8]);
  }
#pragma unroll
  for (int p = 0; p < 2; p++) {
    int n = p * 256 + t;
    gload_lds16(kp2[p], &Ks[0][n * 8]);
    gload_lds16(vp2[p], &Vs[0][n * 8]);
    kp2[p] += 64 * 1024;
    vp2[p] += 64;
  }
  __syncthreads();

  // hoist Q fragments (loop-invariant); Qs LDS dead afterwards
  bf16x8 aq[2][2];
#pragma unroll
  for (int i = 0; i < 2; i++)
#pragma unroll
    for (int ks = 0; ks < 2; ks++)
      aq[i][ks] = *(const bf16x8*)&QPs[(w * 32 + i * 16 + ql) * 64 + ((ks * 4 + qd) ^ sw) * 8];
  __syncthreads();  // all aq reads done before any wave writes P into QPs

  f32x4 accO[2][4] = {};
  float lro2[2] = {0.f, 0.f};  // denom partials for n = w*32 + i*16 + ql (quad-partial)

  int cur = 0;
  for (int lt = 0; lt < 32; ++lt) {
    if (lt + 1 < 32) {
#pragma unroll
      for (int p = 0; p < 2; p++) {
        int n = p * 256 + t;
        gload_lds16(kp2[p], &Ks[1 ^ cur][n * 8]);
        gload_lds16(vp2[p], &Vs[1 ^ cur][n * 8]);
        kp2[p] += 64 * 1024;
        vp2[p] += 64;
      }
    }
    const ushort_t* Kc = Ks[cur];
    const ushort_t* Vc = Vs[cur];

    // S^T = K (Q*0.1803)^T : accS[j][i], rows l = j*16+qd*4+r, cols n = i*16+ql
    f32x4 accS[4][2] = {};
#pragma unroll
    for (int ks = 0; ks < 2; ks++) {
      bf16x8 bk[4];
#pragma unroll
      for (int j = 0; j < 4; j++)
        bk[j] = *(const bf16x8*)&Kc[(j * 16 + ql) * 64 + ((ks * 4 + qd) ^ sw) * 8];
#pragma unroll
      for (int j = 0; j < 4; j++)
#pragma unroll
        for (int i = 0; i < 2; i++)
          accS[j][i] = __builtin_amdgcn_mfma_f32_16x16x32_bf16(bk[j], aq[i][ks], accS[j][i], 0, 0, 0);
    }

    // p = exp2(s_hat); denom += p; pack 4 consecutive l -> one b64 P-write
#pragma unroll
    for (int j = 0; j < 4; j++)
#pragma unroll
      for (int i = 0; i < 2; i++) {
        f32x4 p;
#pragma unroll
        for (int r = 0; r < 4; r++) {
          p[r] = __builtin_amdgcn_exp2f(accS[j][i][r]);
          lro2[i] += p[r];
        }
        const int n = w * 32 + i * 16 + ql;
        // l = j*16 + qd*4 + r; 16B chunk c = j*2 + (qd>>1), swizzled c^(n&7)=c^sw
        const int coff = (((j * 2 + (qd >> 1)) ^ sw) << 3) + ((qd & 1) << 2);
        uint2 pk; pk.x = f2bf2(p[0], p[1]); pk.y = f2bf2(p[2], p[3]);
        *(uint2*)&QPs[n * 64 + coff] = pk;
      }

    // O += P V (P rows intra-wave; V^T B-frags from Vs)
#pragma unroll
    for (int ks = 0; ks < 2; ks++) {
      bf16x8 ap[2], bv[4];
#pragma unroll
      for (int i = 0; i < 2; i++)
        ap[i] = *(const bf16x8*)&QPs[(w * 32 + i * 16 + ql) * 64 + ((ks * 4 + qd) ^ sw) * 8];
#pragma unroll
      for (int jo = 0; jo < 4; jo++)
        bv[jo] = *(const bf16x8*)&Vc[(jo * 16 + ql) * 64 + ((ks * 4 + qd) ^ sw) * 8];
#pragma unroll
      for (int i = 0; i < 2; i++)
#pragma unroll
        for (int jo = 0; jo < 4; jo++)
          accO[i][jo] = __builtin_amdgcn_mfma_f32_16x16x32_bf16(ap[i], bv[jo], accO[i][jo], 0, 0, 0);
    }

    __syncthreads();  // K/V[cur] readers done + next-tile loads drained
    cur ^= 1;
  }

  // finish denominators: sum across quads (each quad held disjoint l ranges)
  float dn[2];
#pragma unroll
  for (int i = 0; i < 2; i++) {
    float l = lro2[i];
    l += __shfl_xor(l, 16);
    l += __shfl_xor(l, 32);
    dn[i] = l + 1.0f;  // +1: implicit zero logit of softmax-1
  }

#pragma unroll
  for (int i = 0; i < 2; i++)
#pragma unroll
    for (int r = 0; r < 4; r++) {
      // denom for row n' = qd*4+r lives in lane ql = n' (quad-uniform after reduce)
      const float inv = 1.0f / __shfl(dn[i], qd * 4 + r);
      const int row = n0 + w * 32 + i * 16 + qd * 4 + r;
#pragma unroll
      for (int jo = 0; jo < 4; jo++)
        Og[((size_t)b * 2048 + row) * 1024 + h * 64 + jo * 16 + ql] =
            f2bf(accO[i][jo][r] * inv);
    }
}

// ---------------- launch ----------------
extern "C" void kernel_launch(void* const* d_in, const int* in_sizes, int n_in,
                              void* d_out, int out_size, void* d_ws, size_t ws_size,
                              hipStream_t stream) {
  const float* x_q = (const float*)d_in[0];
  const float* x_kv = (const float*)d_in[1];
  const float* qn_g = (const float*)d_in[2];
  const float* qn_b = (const float*)d_in[3];
  const float* kvn_g = (const float*)d_in[4];
  const float* kvn_b = (const float*)d_in[5];
  const float* Wq = (const float*)d_in[6];
  const float* bq = (const float*)d_in[7];
  const float* Wk = (const float*)d_in[8];
  const float* bk = (const float*)d_in[9];
  const float* Wv = (const float*)d_in[10];
  const float* bv = (const float*)d_in[11];
  const float* Wo = (const float*)d_in[12];
  const float* bo = (const float*)d_in[13];
  const float* n2_g = (const float*)d_in[14];
  const float* n2_b = (const float*)d_in[15];
  const float* W1 = (const float*)d_in[16];
  const float* b1 = (const float*)d_in[17];
  const float* W2 = (const float*)d_in[18];
  const float* b2 = (const float*)d_in[19];

  char* ws = (char*)d_ws;
  const size_t MB = 1ull << 20;
  ushort_t* WQKVB = (ushort_t*)(ws + 0 * MB);  // 6 MB ([Wq;Wk;Wv], 3072x1024)
  ushort_t* WoB = (ushort_t*)(ws + 6 * MB);    // 2 MB
  ushort_t* W1B = (ushort_t*)(ws + 8 * MB);    // 8 MB
  ushort_t* W2B = (ushort_t*)(ws + 16 * MB);   // 8 MB
  ushort_t* LNQ = (ushort_t*)(ws + 24 * MB);
  ushort_t* LNKV = (ushort_t*)(ws + 32 * MB);
  ushort_t* Qb = (ushort_t*)(ws + 40 * MB);
  ushort_t* Kb = (ushort_t*)(ws + 48 * MB);
  ushort_t* VTb = (ushort_t*)(ws + 56 * MB);
  ushort_t* AOb = (ushort_t*)(ws + 64 * MB);
  float* Xf = (float*)(ws + 72 * MB);          // 16 MB
  ushort_t* LN2 = (ushort_t*)(ws + 88 * MB);
  ushort_t* Hb = (ushort_t*)(ws + 24 * MB);    // 32 MB, overlays LNQ/LNKV/Qb/Kb (dead by MLP1)

  // fold softmax scale (1/8) and exp->exp2 (log2 e) into the Q projection
  const float QSCALE = 0.18033688011112042f;  // 0.125 * log2(e)

  cvt_all<<<12288, 256, 0, stream>>>(Wq, Wk, Wv, Wo, W1, W2, WQKVB, WoB, W1B, W2B);
  ln_fused<<<8192, 256, 0, stream>>>(x_q, x_kv, qn_g, qn_b, kvn_g, kvn_b, LNQ, LNKV);

  // merged Q+K+V projection: N=3072, A = LNQ for n<1024 else LNKV
  gemm_bt<128, 32, EPI_QKV><<<dim3(24, 32), 256, 0, stream>>>(
      LNQ, LNKV, WQKVB, bq, bk, bv, nullptr, Qb, Kb, VTb, 4096, 3072, 1024, QSCALE);

  flash_attn<<<dim3(16, 32), 256, 0, stream>>>(Qb, Kb, VTb, AOb);

  gemm_bt<64, 64, EPI_RESID><<<dim3(16, 32), 256, 0, stream>>>(
      AOb, nullptr, WoB, bo, nullptr, nullptr, x_q, Xf, nullptr, nullptr,
      4096, 1024, 1024, 1.0f);
  ln_bf16<<<4096, 256, 0, stream>>>(Xf, n2_g, n2_b, LN2);
  gemm_bt<128, 32, EPI_GELU><<<dim3(32, 32), 256, 0, stream>>>(
      LN2, nullptr, W1B, b1, nullptr, nullptr, nullptr, Hb, nullptr, nullptr,
      4096, 4096, 1024, 1.0f);
  gemm_bt<64, 64, EPI_RESID><<<dim3(16, 32), 256, 0, stream>>>(
      Hb, nullptr, W2B, b2, nullptr, nullptr, Xf, (float*)d_out, nullptr, nullptr,
      4096, 1024, 4096, 1.0f);
}